// Round 3
// baseline (180.981 us; speedup 1.0000x reference)
//
#include <hip/hip_runtime.h>

#define BIGF 1e9f
#define TT 512
#define DD 256
#define NB 64
#define DROWS 1088    // diag rows per batch (1023 used + prefetch overrun pad)
#define SAK 40        // LDS row stride in bf16 (32 data + 8 pad)
#define CST 66        // C-tile LDS stride in floats
#define NDP 64        // consumer (DP) blocks, blockIdx 0..63
#define NPROD 768     // producer blocks, 2 tiles each
#define CNT_OFF (18 * 1024 * 1024)  // counters live past diag (17.83 MB) in the 256 MiB ws

typedef float floatx16 __attribute__((ext_vector_type(16)));
typedef __bf16 bf16x8 __attribute__((ext_vector_type(8)));

// ---------- DPP wave shifts: lane i <- lane i-1 (shr) / lane i+1 (shl); invalid lanes get `oldv`
__device__ __forceinline__ float dpp_wave_shr1(float x, float oldv) {
  int r = __builtin_amdgcn_update_dpp(__builtin_bit_cast(int, oldv),
                                      __builtin_bit_cast(int, x),
                                      0x138, 0xF, 0xF, false);  // WAVE_SHR1
  return __builtin_bit_cast(float, r);
}
__device__ __forceinline__ float dpp_wave_shl1(float x, float oldv) {
  int r = __builtin_amdgcn_update_dpp(__builtin_bit_cast(int, oldv),
                                      __builtin_bit_cast(int, x),
                                      0x130, 0xF, 0xF, false);  // WAVE_SHL1
  return __builtin_bit_cast(float, r);
}

// ---------- Fused kernel: 768 producer blocks (banded cost tiles) + 64 DP consumer blocks ----
// Producers: identical to the verified round-2 cost path (2 tiles each, batch-major per XCD,
// MFMA + fused norms, LDS-transposed diag-major coalesced stores, m==0 corner paint), plus a
// per-tile agent-scope RELEASE atomicAdd on cnt[b] after the tile-end __syncthreads() (which
// drains all waves' vmcnt; the release RMW writes back dirty L2 -> cross-XCD visible).
// Consumers: block b (< 64) spins on cnt[b]==24 with relaxed agent loads (+s_sleep), does one
// agent ACQUIRE fence (L2 inv -> no stale lines), then runs the DP while later batches' cost
// tiles are still computing. Deadlock-free: 64 spinners << residency capacity; producers never
// wait on consumers. Correct under any workgroup->XCD mapping (Guideline 16).
__global__ __launch_bounds__(256) void dtw_fused(const float* __restrict__ x1,
                                                 const float* __restrict__ x2,
                                                 float* __restrict__ diag,
                                                 unsigned* __restrict__ cnt,
                                                 float* __restrict__ out) {
  // 64*CST floats = 16896 B; first 10240 B double as sA/sB bf16 staging during the K-loop
  __shared__ __align__(16) float sC[64 * CST];

  if (blockIdx.x < NDP) {
    // ================= DP consumer =================
    if (threadIdx.x >= 64) return;  // one wave; no __syncthreads on this path
    const int b = blockIdx.x;       // b%8 == blockIdx%8 -> same XCD as batch b's producers
    const int l = threadIdx.x;

    while (__hip_atomic_load(cnt + b, __ATOMIC_RELAXED, __HIP_MEMORY_SCOPE_AGENT) != 24u)
      __builtin_amdgcn_s_sleep(2);
    __builtin_amdgcn_fence(__ATOMIC_ACQUIRE, "agent");

    const bool inv_odd = (l >= 50);   // k=2l+1 > 100
    const bool inv_even = (l >= 51);  // k=2l   > 100
    const float* base = diag + (size_t)b * (DROWS * 64);
    const float* pO = base + 64 + l;   // d = 1
    const float* pE = base + 128 + l;  // d = 2
    float cr[64];
#pragma unroll
    for (int t = 0; t < 32; ++t) {
      cr[2 * t] = *pO; pO += 128;      // odd d = 1,3,...,63
      cr[2 * t + 1] = *pE; pE += 128;  // even d = 2,4,...,64
    }
    float prev2 = BIGF;
    const float c00 = base[25];          // cost(0,0) lives at d=0, lane 25
    float prev1 = (l == 25) ? c00 : BIGF;
    float ans = BIGF;
    for (int itr = 0; itr < 16; ++itr) {
#pragma unroll
      for (int u = 0; u < 32; ++u) {
        // odd diagonal: d = 64*itr + 2u + 1
        const float c1 = inv_odd ? BIGF : cr[2 * u];
        cr[2 * u] = *pO; pO += 128;  // prefetch 64 diagonals ahead (overrun stays inside ws)
        const float sh = dpp_wave_shl1(prev1, BIGF);
        const float m3 = fminf(fminf(prev1, sh), prev2);
        prev2 = prev1;
        prev1 = c1 + m3;
        // even diagonal: d = 64*itr + 2u + 2
        const float c2 = inv_even ? BIGF : cr[2 * u + 1];
        cr[2 * u + 1] = *pE; pE += 128;
        const float sh2 = dpp_wave_shr1(prev1, BIGF);
        const float m32 = fminf(fminf(sh2, prev1), prev2);
        prev2 = prev1;
        prev1 = c2 + m32;
        if (itr == 15 && u == 30) ans = prev1;  // d = 1022 -> cell (511,511) at lane 25
      }
    }
    if (l == 25) out[b] = ans;
    return;
  }

  // ================= producer =================
  const int p = blockIdx.x - NDP;  // 0..767
  const int x = p & 7;             // XCD affinity heuristic (perf only)
  const int pl = p >> 3;           // 0..95 within XCD

  __bf16* sA = (__bf16*)sC;
  __bf16* sB = ((__bf16*)sC) + 64 * SAK;
  __shared__ float rA[64];  // 1/max(||x1_i||, eps) per tile row
  __shared__ float rB[64];

  const int t = threadIdx.x;
  const int lane = t & 63;
  const int w = t >> 6;       // wave 0..3
  const int wi = w >> 1;      // i-subtile (0/1)
  const int wj = w & 1;       // j-subtile (0/1)
  const int ln = lane & 31;
  const int kh = lane >> 5;   // k-half (0/1)

  // thread-static staging/fragment addresses (tile-independent)
  const int sr = t >> 2;      // staging row
  const int sq = t & 3;       // staging quarter
  __bf16* dA = sA + sr * SAK + sq * 8;
  __bf16* dB = sB + sr * SAK + sq * 8;
  const __bf16* fAp = sA + (wi * 32 + ln) * SAK + kh * 8;
  const __bf16* fBp = sB + (wj * 32 + ln) * SAK + kh * 8;

  for (int kt = 0; kt < 2; ++kt) {
    const int T = pl + 96 * kt;     // 0..191, batch-major within XCD
    const int bhi = T / 24;         // 0..7
    const int m = T - bhi * 24;     // 0..23
    const int b = bhi * 8 + x;      // batch, b%8 == XCD
    const int it = m & 7;           // i-tile
    const int jt = m >> 3;          // j-tile 0..2
    const int i0 = it * 64;
    const int j0 = i0 - 50 + jt * 64;

    float* db = diag + (size_t)b * (DROWS * 64);

    // corner paint (one tile per batch; disjoint from all valid-cell writes -> no sync)
    if (m == 0) {
      for (int r = w; r < 180; r += 4) {
        const int d = (r < 64) ? r : r + 908;  // [0,64) U [972,1088)
        const int pp = d & 1;
        const int i = (d >> 1) + lane + pp - 25;
        const int j = d - i;
        const int k = 2 * lane + pp;
        if (k > 100 || (unsigned)i >= TT || (unsigned)j >= TT)
          db[(size_t)d * 64 + lane] = BIGF;
      }
    }

    const float* x1b = x1 + (size_t)b * (TT * DD);
    const float* x2b = x2 + (size_t)b * (TT * DD);
    int gj = j0 + sr;
    gj = gj < 0 ? 0 : (gj > TT - 1 ? TT - 1 : gj);
    const float* pAg = x1b + (size_t)(i0 + sr) * DD + sq * 8;
    const float* pBg = x2b + (size_t)gj * DD + sq * 8;

    floatx16 acc = {};
    float pa = 0.f, pb = 0.f;  // sum-of-squares partials (fp32, from original data)

    for (int kc = 0; kc < DD; kc += 32) {
      const float4 a0 = *(const float4*)(pAg + kc);
      const float4 a1 = *(const float4*)(pAg + kc + 4);
      const float4 b0 = *(const float4*)(pBg + kc);
      const float4 b1 = *(const float4*)(pBg + kc + 4);
      pa += a0.x * a0.x + a0.y * a0.y + a0.z * a0.z + a0.w * a0.w;
      pa += a1.x * a1.x + a1.y * a1.y + a1.z * a1.z + a1.w * a1.w;
      pb += b0.x * b0.x + b0.y * b0.y + b0.z * b0.z + b0.w * b0.w;
      pb += b1.x * b1.x + b1.y * b1.y + b1.z * b1.z + b1.w * b1.w;
      // barrier also fences the previous tile's sC reads before we overwrite sA/sB (alias)
      __syncthreads();
      {
        bf16x8 va, vb;
        va[0] = (__bf16)a0.x; va[1] = (__bf16)a0.y; va[2] = (__bf16)a0.z; va[3] = (__bf16)a0.w;
        va[4] = (__bf16)a1.x; va[5] = (__bf16)a1.y; va[6] = (__bf16)a1.z; va[7] = (__bf16)a1.w;
        vb[0] = (__bf16)b0.x; vb[1] = (__bf16)b0.y; vb[2] = (__bf16)b0.z; vb[3] = (__bf16)b0.w;
        vb[4] = (__bf16)b1.x; vb[5] = (__bf16)b1.y; vb[6] = (__bf16)b1.z; vb[7] = (__bf16)b1.w;
        *(bf16x8*)dA = va;
        *(bf16x8*)dB = vb;
      }
      __syncthreads();
      const bf16x8 fa0 = *(const bf16x8*)fAp;
      const bf16x8 fb0 = *(const bf16x8*)fBp;
      const bf16x8 fa1 = *(const bf16x8*)(fAp + 16);
      const bf16x8 fb1 = *(const bf16x8*)(fBp + 16);
      acc = __builtin_amdgcn_mfma_f32_32x32x16_bf16(fa0, fb0, acc, 0, 0, 0);
      acc = __builtin_amdgcn_mfma_f32_32x32x16_bf16(fa1, fb1, acc, 0, 0, 0);
    }

    // reduce sumsq across the 4 staging threads of each row (lanes t^1, t^2 share sr)
    pa += __shfl_xor(pa, 1, 64); pa += __shfl_xor(pa, 2, 64);
    pb += __shfl_xor(pb, 1, 64); pb += __shfl_xor(pb, 2, 64);
    if (sq == 0) {
      rA[sr] = 1.0f / fmaxf(sqrtf(pa), 1e-8f);
      rB[sr] = 1.0f / fmaxf(sqrtf(pb), 1e-8f);
    }
    __syncthreads();  // rA/rB ready; all waves past their last sA/sB reads -> reuse as sC

    // scale and stage C tile in LDS: C layout col=lane&31 (rj), row=(reg&3)+8*(reg>>2)+4*kh (ri)
    {
      const int rj = wj * 32 + ln;
      const float r2 = rB[rj];
#pragma unroll
      for (int reg = 0; reg < 16; ++reg) {
        const int ri = wi * 32 + (reg & 3) + 8 * (reg >> 2) + 4 * kh;
        sC[ri * CST + rj] = 1.0f - acc[reg] * rA[ri] * r2;
      }
    }
    __syncthreads();

    // diag-major coalesced stores: wave w handles rows r = w, w+4, ..., w+124 (d = d0 + r).
    // lane l holds band cell k = 2l + (d&1); LDS lane-stride 65 words -> conflict-free.
    {
      const int d0 = i0 + j0;
      const int a65 = 65 * lane;
#pragma unroll 4
      for (int rr = 0; rr < 32; ++rr) {
        const int r = 4 * rr + w;              // 0..127
        const int d = d0 + r;                  // corner tiles: fully masked when OOB
        const int pp = d & 1;
        const int roff = ((d + pp - 50) >> 1) - i0;   // ri at lane 0
        const int ri = lane + roff;
        const int rj = r - ri;
        const int kband = 2 * lane + pp;
        const int jg = j0 + rj;
        if (((unsigned)ri < 64u) & ((unsigned)rj < 64u) & (kband <= 100) &
            ((unsigned)jg < (unsigned)TT)) {
          db[(size_t)d * 64 + lane] = sC[a65 + 65 * roff + r];
        }
      }
    }

    // tile done: drain all waves' stores (compiler emits vmcnt(0) before s_barrier),
    // then RELEASE this tile for batch b (agent scope: writes back dirty L2 -> visible
    // to the consumer on any XCD).
    __syncthreads();
    if (t == 0)
      __hip_atomic_fetch_add(cnt + b, 1u, __ATOMIC_RELEASE, __HIP_MEMORY_SCOPE_AGENT);
  }
}

extern "C" void kernel_launch(void* const* d_in, const int* in_sizes, int n_in,
                              void* d_out, int out_size, void* d_ws, size_t ws_size,
                              hipStream_t stream) {
  const float* x1 = (const float*)d_in[0];
  const float* x2 = (const float*)d_in[1];
  float* out = (float*)d_out;
  float* diag = (float*)d_ws;  // 64*1088*64 floats = 17.8 MB
  unsigned* cnt = (unsigned*)((char*)d_ws + CNT_OFF);  // 64 per-batch tile counters

  hipMemsetAsync(cnt, 0, NDP * sizeof(unsigned), stream);  // capture-safe graph node
  dtw_fused<<<NDP + NPROD, 256, 0, stream>>>(x1, x2, diag, cnt, out);
}

// Round 4
// 153.835 us; speedup vs baseline: 1.1765x; 1.1765x over previous
//
#include <hip/hip_runtime.h>

#define BIGF 1e9f
#define TT 512
#define DD 256
#define NB 64
#define DROWS 1088    // diag rows per batch (1023 used + feeder overrun pad)
#define SAK 40        // LDS row stride in bf16 (32 data + 8 pad)
#define CST 66        // C-tile LDS stride in floats
#define CH 64         // diagonals per DP chunk

typedef float floatx16 __attribute__((ext_vector_type(16)));
typedef __bf16 bf16x8 __attribute__((ext_vector_type(8)));

// ---------- DPP wave shifts: lane i <- lane i-1 (shr) / lane i+1 (shl); invalid lanes get `oldv`
__device__ __forceinline__ float dpp_wave_shr1(float x, float oldv) {
  int r = __builtin_amdgcn_update_dpp(__builtin_bit_cast(int, oldv),
                                      __builtin_bit_cast(int, x),
                                      0x138, 0xF, 0xF, false);  // WAVE_SHR1
  return __builtin_bit_cast(float, r);
}
__device__ __forceinline__ float dpp_wave_shl1(float x, float oldv) {
  int r = __builtin_amdgcn_update_dpp(__builtin_bit_cast(int, oldv),
                                      __builtin_bit_cast(int, x),
                                      0x130, 0xF, 0xF, false);  // WAVE_SHL1
  return __builtin_bit_cast(float, r);
}

// ---------- Kernel B: banded cost via bf16 MFMA + fused norms (round-2 verbatim) ----------
__global__ __launch_bounds__(256) void cost_kernel(const float* __restrict__ x1,
                                                   const float* __restrict__ x2,
                                                   float* __restrict__ diag) {
  const int p = blockIdx.x;   // 0..767
  const int x = p & 7;        // XCD
  const int pl = p >> 3;      // 0..95 within XCD

  __shared__ __align__(16) float sC[64 * CST];
  __bf16* sA = (__bf16*)sC;
  __bf16* sB = ((__bf16*)sC) + 64 * SAK;
  __shared__ float rA[64];
  __shared__ float rB[64];

  const int t = threadIdx.x;
  const int lane = t & 63;
  const int w = t >> 6;
  const int wi = w >> 1;
  const int wj = w & 1;
  const int ln = lane & 31;
  const int kh = lane >> 5;

  const int sr = t >> 2;
  const int sq = t & 3;
  __bf16* dA = sA + sr * SAK + sq * 8;
  __bf16* dB = sB + sr * SAK + sq * 8;
  const __bf16* fAp = sA + (wi * 32 + ln) * SAK + kh * 8;
  const __bf16* fBp = sB + (wj * 32 + ln) * SAK + kh * 8;

  for (int kt = 0; kt < 2; ++kt) {
    const int T = pl + 96 * kt;     // 0..191, batch-major within XCD
    const int bhi = T / 24;
    const int m = T - bhi * 24;
    const int b = bhi * 8 + x;
    const int it = m & 7;
    const int jt = m >> 3;
    const int i0 = it * 64;
    const int j0 = i0 - 50 + jt * 64;

    float* db = diag + (size_t)b * (DROWS * 64);

    if (m == 0) {
      for (int r = w; r < 180; r += 4) {
        const int d = (r < 64) ? r : r + 908;  // [0,64) U [972,1088)
        const int pp = d & 1;
        const int i = (d >> 1) + lane + pp - 25;
        const int j = d - i;
        const int k = 2 * lane + pp;
        if (k > 100 || (unsigned)i >= TT || (unsigned)j >= TT)
          db[(size_t)d * 64 + lane] = BIGF;
      }
    }

    const float* x1b = x1 + (size_t)b * (TT * DD);
    const float* x2b = x2 + (size_t)b * (TT * DD);
    int gj = j0 + sr;
    gj = gj < 0 ? 0 : (gj > TT - 1 ? TT - 1 : gj);
    const float* pAg = x1b + (size_t)(i0 + sr) * DD + sq * 8;
    const float* pBg = x2b + (size_t)gj * DD + sq * 8;

    floatx16 acc = {};
    float pa = 0.f, pb = 0.f;

    for (int kc = 0; kc < DD; kc += 32) {
      const float4 a0 = *(const float4*)(pAg + kc);
      const float4 a1 = *(const float4*)(pAg + kc + 4);
      const float4 b0 = *(const float4*)(pBg + kc);
      const float4 b1 = *(const float4*)(pBg + kc + 4);
      pa += a0.x * a0.x + a0.y * a0.y + a0.z * a0.z + a0.w * a0.w;
      pa += a1.x * a1.x + a1.y * a1.y + a1.z * a1.z + a1.w * a1.w;
      pb += b0.x * b0.x + b0.y * b0.y + b0.z * b0.z + b0.w * b0.w;
      pb += b1.x * b1.x + b1.y * b1.y + b1.z * b1.z + b1.w * b1.w;
      __syncthreads();
      {
        bf16x8 va, vb;
        va[0] = (__bf16)a0.x; va[1] = (__bf16)a0.y; va[2] = (__bf16)a0.z; va[3] = (__bf16)a0.w;
        va[4] = (__bf16)a1.x; va[5] = (__bf16)a1.y; va[6] = (__bf16)a1.z; va[7] = (__bf16)a1.w;
        vb[0] = (__bf16)b0.x; vb[1] = (__bf16)b0.y; vb[2] = (__bf16)b0.z; vb[3] = (__bf16)b0.w;
        vb[4] = (__bf16)b1.x; vb[5] = (__bf16)b1.y; vb[6] = (__bf16)b1.z; vb[7] = (__bf16)b1.w;
        *(bf16x8*)dA = va;
        *(bf16x8*)dB = vb;
      }
      __syncthreads();
      const bf16x8 fa0 = *(const bf16x8*)fAp;
      const bf16x8 fb0 = *(const bf16x8*)fBp;
      const bf16x8 fa1 = *(const bf16x8*)(fAp + 16);
      const bf16x8 fb1 = *(const bf16x8*)(fBp + 16);
      acc = __builtin_amdgcn_mfma_f32_32x32x16_bf16(fa0, fb0, acc, 0, 0, 0);
      acc = __builtin_amdgcn_mfma_f32_32x32x16_bf16(fa1, fb1, acc, 0, 0, 0);
    }

    pa += __shfl_xor(pa, 1, 64); pa += __shfl_xor(pa, 2, 64);
    pb += __shfl_xor(pb, 1, 64); pb += __shfl_xor(pb, 2, 64);
    if (sq == 0) {
      rA[sr] = 1.0f / fmaxf(sqrtf(pa), 1e-8f);
      rB[sr] = 1.0f / fmaxf(sqrtf(pb), 1e-8f);
    }
    __syncthreads();

    {
      const int rj = wj * 32 + ln;
      const float r2 = rB[rj];
#pragma unroll
      for (int reg = 0; reg < 16; ++reg) {
        const int ri = wi * 32 + (reg & 3) + 8 * (reg >> 2) + 4 * kh;
        sC[ri * CST + rj] = 1.0f - acc[reg] * rA[ri] * r2;
      }
    }
    __syncthreads();

    {
      const int d0 = i0 + j0;
      const int a65 = 65 * lane;
#pragma unroll 4
      for (int rr = 0; rr < 32; ++rr) {
        const int r = 4 * rr + w;
        const int d = d0 + r;
        const int pp = d & 1;
        const int roff = ((d + pp - 50) >> 1) - i0;
        const int ri = lane + roff;
        const int rj = r - ri;
        const int kband = 2 * lane + pp;
        const int jg = j0 + rj;
        if (((unsigned)ri < 64u) & ((unsigned)rj < 64u) & (kband <= 100) &
            ((unsigned)jg < (unsigned)TT)) {
          db[(size_t)d * 64 + lane] = sC[a65 + 65 * roff + r];
        }
      }
    }
  }
}

// ---------- Kernel C: DP with LDS feeder pipeline ----------
// 64 blocks x 256 threads. Wave 0 runs the serial DP chain reading costs from LDS
// (ds_read_b32, statically unrolled -> fine-grained lgkmcnt pipelining under the
// ~14-cyc/step VALU chain). Waves 1-3 (192 threads) stream the NEXT 64-diagonal chunk
// (16 KB, fully coalesced dwordx4) from global into the other half of a double-buffered
// LDS tile. One __syncthreads per chunk; writers touch buf[(c+1)&1] while the chain reads
// buf[c&1] -> disjoint between barriers, race-free by construction.
// This moves ALL global-load latency (the exposed ~80-100 cyc/step that made the old
// single-wave version ~40 us) onto feeder waves that have 6 independent loads in flight.
__global__ __launch_bounds__(256) void dtw_dp_kernel(const float* __restrict__ diag,
                                                     float* __restrict__ out) {
  __shared__ __align__(16) float sD[2][CH][64];  // 32 KB double buffer
  const int b = blockIdx.x;
  const int t = threadIdx.x;
  const float* base = diag + (size_t)b * (DROWS * 64);

  // ---- feeder helper (waves 1..3): chunk c covers diagonals d = 64c+1 .. 64c+64 ----
  // 1024 float4 items; item = tf + 192*k (k=0..5, guard); s = item>>4, col4 = item&15.
  const int tf = t - 64;

  // prologue: feeders fill chunk 0 into sD[0]
  if (t >= 64) {
    const float* src = base + 64;  // d = 1
    float4 v[6];
#pragma unroll
    for (int k = 0; k < 6; ++k) {
      const int item = tf + 192 * k;
      if (item < 1024)
        v[k] = *(const float4*)(src + (size_t)(item >> 4) * 64 + (item & 15) * 4);
    }
#pragma unroll
    for (int k = 0; k < 6; ++k) {
      const int item = tf + 192 * k;
      if (item < 1024)
        *(float4*)&sD[0][item >> 4][(item & 15) * 4] = v[k];
    }
  }

  // wave-0 DP state (set up while feeders issue the prologue loads)
  const int l = t;  // only meaningful for t < 64
  const bool inv_odd = (l >= 50);   // k=2l+1 > 100
  const bool inv_even = (l >= 51);  // k=2l   > 100
  float prev2 = BIGF;
  float prev1 = BIGF;
  if (t < 64) prev1 = (l == 25) ? base[25] : BIGF;  // cost(0,0) at d=0, lane 25
  float ans = BIGF;

  __syncthreads();

  for (int c = 0; c < 16; ++c) {
    if (t >= 64) {
      // feed chunk c+1 into sD[(c+1)&1] (skip past the last chunk)
      if (c < 15) {
        const float* src = base + (size_t)(64 * (c + 1) + 1) * 64;
        float4 v[6];
#pragma unroll
        for (int k = 0; k < 6; ++k) {
          const int item = tf + 192 * k;
          if (item < 1024)
            v[k] = *(const float4*)(src + (size_t)(item >> 4) * 64 + (item & 15) * 4);
        }
        float* dst = &sD[(c + 1) & 1][0][0];
#pragma unroll
        for (int k = 0; k < 6; ++k) {
          const int item = tf + 192 * k;
          if (item < 1024)
            *(float4*)(dst + (size_t)(item >> 4) * 64 + (item & 15) * 4) = v[k];
        }
      }
    } else {
      // chain: 64 diagonals from sD[c&1]; d = 64c+1+s (s even -> odd d, s odd -> even d)
      const float* row = &sD[c & 1][0][0] + l;
#pragma unroll
      for (int s = 0; s < 64; s += 2) {
        // odd diagonal
        const float c1 = inv_odd ? BIGF : row[s * 64];
        const float sh = dpp_wave_shl1(prev1, BIGF);
        const float m3 = fminf(fminf(prev1, sh), prev2);
        prev2 = prev1;
        prev1 = c1 + m3;
        // even diagonal
        const float c2 = inv_even ? BIGF : row[(s + 1) * 64];
        const float sh2 = dpp_wave_shr1(prev1, BIGF);
        const float m32 = fminf(fminf(sh2, prev1), prev2);
        prev2 = prev1;
        prev1 = c2 + m32;
        if (c == 15 && s == 60) ans = prev1;  // d = 1022 -> cell (511,511) at lane 25
        // s = 62 pair (d = 1023,1024) runs on pad data: finite poison, ans already captured
      }
    }
    __syncthreads();
  }

  if (t == 25) out[b] = ans;
}

extern "C" void kernel_launch(void* const* d_in, const int* in_sizes, int n_in,
                              void* d_out, int out_size, void* d_ws, size_t ws_size,
                              hipStream_t stream) {
  const float* x1 = (const float*)d_in[0];
  const float* x2 = (const float*)d_in[1];
  float* out = (float*)d_out;
  float* diag = (float*)d_ws;  // 64*1088*64 floats = 17.8 MB

  cost_kernel<<<768, 256, 0, stream>>>(x1, x2, diag);
  dtw_dp_kernel<<<NB, 256, 0, stream>>>(diag, out);
}

// Round 6
// 143.403 us; speedup vs baseline: 1.2620x; 1.0727x over previous
//
#include <hip/hip_runtime.h>

#define BIGF 1e9f
#define TT 512
#define DD 256
#define NB 64
#define DROWS 1088    // diag rows per batch (1023 used + prefetch overrun pad)
#define SAK 40        // LDS row stride in bf16 (32 data + 8 pad)
#define CST 66        // C-tile LDS stride in floats

typedef float floatx16 __attribute__((ext_vector_type(16)));
typedef __bf16 bf16x8 __attribute__((ext_vector_type(8)));

// ---------- DPP wave shifts: lane i <- lane i-1 (shr) / lane i+1 (shl); invalid lanes get `oldv`
__device__ __forceinline__ float dpp_wave_shr1(float x, float oldv) {
  int r = __builtin_amdgcn_update_dpp(__builtin_bit_cast(int, oldv),
                                      __builtin_bit_cast(int, x),
                                      0x138, 0xF, 0xF, false);  // WAVE_SHR1
  return __builtin_bit_cast(float, r);
}
__device__ __forceinline__ float dpp_wave_shl1(float x, float oldv) {
  int r = __builtin_amdgcn_update_dpp(__builtin_bit_cast(int, oldv),
                                      __builtin_bit_cast(int, x),
                                      0x130, 0xF, 0xF, false);  // WAVE_SHL1
  return __builtin_bit_cast(float, r);
}

// ---------- Kernel B: banded cost via bf16 MFMA + fused norms (round-2 verbatim) ----------
__global__ __launch_bounds__(256) void cost_kernel(const float* __restrict__ x1,
                                                   const float* __restrict__ x2,
                                                   float* __restrict__ diag) {
  const int p = blockIdx.x;   // 0..767
  const int x = p & 7;        // XCD
  const int pl = p >> 3;      // 0..95 within XCD

  __shared__ __align__(16) float sC[64 * CST];
  __bf16* sA = (__bf16*)sC;
  __bf16* sB = ((__bf16*)sC) + 64 * SAK;
  __shared__ float rA[64];
  __shared__ float rB[64];

  const int t = threadIdx.x;
  const int lane = t & 63;
  const int w = t >> 6;
  const int wi = w >> 1;
  const int wj = w & 1;
  const int ln = lane & 31;
  const int kh = lane >> 5;

  const int sr = t >> 2;
  const int sq = t & 3;
  __bf16* dA = sA + sr * SAK + sq * 8;
  __bf16* dB = sB + sr * SAK + sq * 8;
  const __bf16* fAp = sA + (wi * 32 + ln) * SAK + kh * 8;
  const __bf16* fBp = sB + (wj * 32 + ln) * SAK + kh * 8;

  for (int kt = 0; kt < 2; ++kt) {
    const int T = pl + 96 * kt;     // 0..191, batch-major within XCD
    const int bhi = T / 24;
    const int m = T - bhi * 24;
    const int b = bhi * 8 + x;
    const int it = m & 7;
    const int jt = m >> 3;
    const int i0 = it * 64;
    const int j0 = i0 - 50 + jt * 64;

    float* db = diag + (size_t)b * (DROWS * 64);

    if (m == 0) {
      for (int r = w; r < 180; r += 4) {
        const int d = (r < 64) ? r : r + 908;  // [0,64) U [972,1088)
        const int pp = d & 1;
        const int i = (d >> 1) + lane + pp - 25;
        const int j = d - i;
        const int k = 2 * lane + pp;
        if (k > 100 || (unsigned)i >= TT || (unsigned)j >= TT)
          db[(size_t)d * 64 + lane] = BIGF;
      }
    }

    const float* x1b = x1 + (size_t)b * (TT * DD);
    const float* x2b = x2 + (size_t)b * (TT * DD);
    int gj = j0 + sr;
    gj = gj < 0 ? 0 : (gj > TT - 1 ? TT - 1 : gj);
    const float* pAg = x1b + (size_t)(i0 + sr) * DD + sq * 8;
    const float* pBg = x2b + (size_t)gj * DD + sq * 8;

    floatx16 acc = {};
    float pa = 0.f, pb = 0.f;

    for (int kc = 0; kc < DD; kc += 32) {
      const float4 a0 = *(const float4*)(pAg + kc);
      const float4 a1 = *(const float4*)(pAg + kc + 4);
      const float4 b0 = *(const float4*)(pBg + kc);
      const float4 b1 = *(const float4*)(pBg + kc + 4);
      pa += a0.x * a0.x + a0.y * a0.y + a0.z * a0.z + a0.w * a0.w;
      pa += a1.x * a1.x + a1.y * a1.y + a1.z * a1.z + a1.w * a1.w;
      pb += b0.x * b0.x + b0.y * b0.y + b0.z * b0.z + b0.w * b0.w;
      pb += b1.x * b1.x + b1.y * b1.y + b1.z * b1.z + b1.w * b1.w;
      __syncthreads();
      {
        bf16x8 va, vb;
        va[0] = (__bf16)a0.x; va[1] = (__bf16)a0.y; va[2] = (__bf16)a0.z; va[3] = (__bf16)a0.w;
        va[4] = (__bf16)a1.x; va[5] = (__bf16)a1.y; va[6] = (__bf16)a1.z; va[7] = (__bf16)a1.w;
        vb[0] = (__bf16)b0.x; vb[1] = (__bf16)b0.y; vb[2] = (__bf16)b0.z; vb[3] = (__bf16)b0.w;
        vb[4] = (__bf16)b1.x; vb[5] = (__bf16)b1.y; vb[6] = (__bf16)b1.z; vb[7] = (__bf16)b1.w;
        *(bf16x8*)dA = va;
        *(bf16x8*)dB = vb;
      }
      __syncthreads();
      const bf16x8 fa0 = *(const bf16x8*)fAp;
      const bf16x8 fb0 = *(const bf16x8*)fBp;
      const bf16x8 fa1 = *(const bf16x8*)(fAp + 16);
      const bf16x8 fb1 = *(const bf16x8*)(fBp + 16);
      acc = __builtin_amdgcn_mfma_f32_32x32x16_bf16(fa0, fb0, acc, 0, 0, 0);
      acc = __builtin_amdgcn_mfma_f32_32x32x16_bf16(fa1, fb1, acc, 0, 0, 0);
    }

    pa += __shfl_xor(pa, 1, 64); pa += __shfl_xor(pa, 2, 64);
    pb += __shfl_xor(pb, 1, 64); pb += __shfl_xor(pb, 2, 64);
    if (sq == 0) {
      rA[sr] = 1.0f / fmaxf(sqrtf(pa), 1e-8f);
      rB[sr] = 1.0f / fmaxf(sqrtf(pb), 1e-8f);
    }
    __syncthreads();

    {
      const int rj = wj * 32 + ln;
      const float r2 = rB[rj];
#pragma unroll
      for (int reg = 0; reg < 16; ++reg) {
        const int ri = wi * 32 + (reg & 3) + 8 * (reg >> 2) + 4 * kh;
        sC[ri * CST + rj] = 1.0f - acc[reg] * rA[ri] * r2;
      }
    }
    __syncthreads();

    {
      const int d0 = i0 + j0;
      const int a65 = 65 * lane;
#pragma unroll 4
      for (int rr = 0; rr < 32; ++rr) {
        const int r = 4 * rr + w;
        const int d = d0 + r;
        const int pp = d & 1;
        const int roff = ((d + pp - 50) >> 1) - i0;
        const int ri = lane + roff;
        const int rj = r - ri;
        const int kband = 2 * lane + pp;
        const int jg = j0 + rj;
        if (((unsigned)ri < 64u) & ((unsigned)rj < 64u) & (kband <= 100) &
            ((unsigned)jg < (unsigned)TT)) {
          db[(size_t)d * 64 + lane] = sC[a65 + 65 * roff + r];
        }
      }
    }
  }
}

// ---------- Kernel C: DP with float2 rolling prefetch (2 diagonals per load) ----------
// Single wave per batch, no barriers. Pair p covers diagonals d=2p+1 (odd) and d=2p+2 (even):
// lane l loads float2 at base + (2p+1)*64 + 2l -> the 128 contiguous floats of both rows.
// Redistribution to band layout (lane l needs col l of each row), off the critical chain:
//   element c of the 128-float block lives in lane c>>1, component c&1.
//   odd row  col l -> src lane l>>1,        comp l&1
//   even row col l -> src lane 32+(l>>1),   comp l&1
// 4 __shfl (ds_bpermute) + 2 selects per pair; inputs are 64-pairs-old -> vmcnt satisfied,
// compiler schedules them ahead of the chain. One load per 2 DP steps doubles the latency
// tolerance under the hw ~63-outstanding-VMEM cap: 63 loads ~ 126 rows * ~16 cyc ~ 2000+ cyc,
// vs the old 1-load-per-step scheme (~900 cyc tolerance << ~2500 cyc effective diag latency).
// Chain math / DPP shifts / capture identical to the verified round-2 kernel.
__global__ __launch_bounds__(64, 1) void dtw_dp_kernel(const float* __restrict__ diag,
                                                       float* __restrict__ out) {
  const int b = blockIdx.x;
  const int l = threadIdx.x;
  const bool inv_odd = (l >= 50);   // k=2l+1 > 100
  const bool inv_even = (l >= 51);  // k=2l   > 100
  const float* base = diag + (size_t)b * (DROWS * 64);

  const float* pP = base + 64 + 2 * l;  // pair 0 (d=1,2)
  float2 cr[64];                        // 64 pairs = 128 diagonals buffered
#pragma unroll
  for (int s = 0; s < 64; ++s) {
    cr[s] = *(const float2*)pP;
    pP += 128;  // advance 2 diagonals
  }

  float prev2 = BIGF;
  float prev1 = (l == 25) ? base[25] : BIGF;  // cost(0,0) at d=0, lane 25
  float ans = BIGF;
  const int srcO = l >> 1;         // shfl source for odd row
  const int srcE = 32 + (l >> 1);  // shfl source for even row
  const bool hi = l & 1;

  for (int o = 0; o < 8; ++o) {
#pragma unroll
    for (int u = 0; u < 64; ++u) {   // pair p = 64*o + u; slot index static (rule #20)
      const float2 v = cr[u];
      cr[u] = *(const float2*)pP;    // prefetch pair p+64 (overrun past batch end stays in ws,
      pP += 128;                     //  prefetched-only values are never consumed)
      // redistribute pair to band layout (off-chain)
      const float o0 = __shfl(v.x, srcO, 64);
      const float o1 = __shfl(v.y, srcO, 64);
      const float e0 = __shfl(v.x, srcE, 64);
      const float e1 = __shfl(v.y, srcE, 64);
      const float cO = hi ? o1 : o0;
      const float cE = hi ? e1 : e0;
      // odd diagonal d = 2p+1
      const float c1 = inv_odd ? BIGF : cO;
      const float sh = dpp_wave_shl1(prev1, BIGF);
      const float m3 = fminf(fminf(prev1, sh), prev2);
      prev2 = prev1;
      prev1 = c1 + m3;
      // even diagonal d = 2p+2
      const float c2 = inv_even ? BIGF : cE;
      const float sh2 = dpp_wave_shr1(prev1, BIGF);
      const float m32 = fminf(fminf(sh2, prev1), prev2);
      prev2 = prev1;
      prev1 = c2 + m32;
      if (o == 7 && u == 62) ans = prev1;  // d = 1022 -> cell (511,511) at lane 25
      // pairs 511 (d=1023,1024) run on BIG-painted pad rows; ans already captured
    }
  }
  if (l == 25) out[b] = ans;
}

extern "C" void kernel_launch(void* const* d_in, const int* in_sizes, int n_in,
                              void* d_out, int out_size, void* d_ws, size_t ws_size,
                              hipStream_t stream) {
  const float* x1 = (const float*)d_in[0];
  const float* x2 = (const float*)d_in[1];
  float* out = (float*)d_out;
  float* diag = (float*)d_ws;  // 64*1088*64 floats = 17.8 MB

  cost_kernel<<<768, 256, 0, stream>>>(x1, x2, diag);
  dtw_dp_kernel<<<NB, 64, 0, stream>>>(diag, out);
}

// Round 7
// 126.529 us; speedup vs baseline: 1.4304x; 1.1334x over previous
//
#include <hip/hip_runtime.h>

#define BIGF 1e9f
#define TT 512
#define DD 256
#define NB 64
#define PROWS 580     // per-batch pair-rows (1 d0-row + 511 pairs + 64 prefetch pad + slack)
#define SAK 40        // LDS row stride in bf16 (32 data + 8 pad)
#define CST 66        // C-tile LDS stride in floats

typedef float floatx16 __attribute__((ext_vector_type(16)));
typedef __bf16 bf16x8 __attribute__((ext_vector_type(8)));

// ---------- DPP wave shifts: lane i <- lane i-1 (shr) / lane i+1 (shl); invalid lanes get `oldv`
__device__ __forceinline__ float dpp_wave_shr1(float x, float oldv) {
  int r = __builtin_amdgcn_update_dpp(__builtin_bit_cast(int, oldv),
                                      __builtin_bit_cast(int, x),
                                      0x138, 0xF, 0xF, false);  // WAVE_SHR1
  return __builtin_bit_cast(float, r);
}
__device__ __forceinline__ float dpp_wave_shl1(float x, float oldv) {
  int r = __builtin_amdgcn_update_dpp(__builtin_bit_cast(int, oldv),
                                      __builtin_bit_cast(int, x),
                                      0x130, 0xF, 0xF, false);  // WAVE_SHL1
  return __builtin_bit_cast(float, r);
}

// ---------- pair-interleaved band layout ----------
// Cell (d, k) [k = i-j+50, k and d share parity] lives at:
//   row = 1 + ((d-1)>>1)   (arith shift: d=0 -> row 0)
//   off = row*128 + 2*(k>>1) + ((d-1)&1)
// So pair row p>=1 holds diag d=2p-1 in even components and d=2p in odd components:
// one float2 load at 2l gives lane l BOTH its band cells (k=2l+1 odd-d, k=2l even-d)
// with NO cross-lane redistribution (the round-6 shfl confound eliminated).
// d=0 cell (0,0) lands at off 51 via the same formula.

// ---------- Kernel B: banded cost via bf16 MFMA + fused norms ----------
// Identical to the verified round-2 kernel except the diag write addresses (epilogue +
// corner paint) use the pair-interleaved layout above.
__global__ __launch_bounds__(256) void cost_kernel(const float* __restrict__ x1,
                                                   const float* __restrict__ x2,
                                                   float* __restrict__ diag) {
  const int p = blockIdx.x;   // 0..767
  const int x = p & 7;        // XCD
  const int pl = p >> 3;      // 0..95 within XCD

  __shared__ __align__(16) float sC[64 * CST];
  __bf16* sA = (__bf16*)sC;
  __bf16* sB = ((__bf16*)sC) + 64 * SAK;
  __shared__ float rA[64];
  __shared__ float rB[64];

  const int t = threadIdx.x;
  const int lane = t & 63;
  const int w = t >> 6;
  const int wi = w >> 1;
  const int wj = w & 1;
  const int ln = lane & 31;
  const int kh = lane >> 5;

  const int sr = t >> 2;
  const int sq = t & 3;
  __bf16* dA = sA + sr * SAK + sq * 8;
  __bf16* dB = sB + sr * SAK + sq * 8;
  const __bf16* fAp = sA + (wi * 32 + ln) * SAK + kh * 8;
  const __bf16* fBp = sB + (wj * 32 + ln) * SAK + kh * 8;

  for (int kt = 0; kt < 2; ++kt) {
    const int T = pl + 96 * kt;     // 0..191, batch-major within XCD
    const int bhi = T / 24;
    const int m = T - bhi * 24;
    const int b = bhi * 8 + x;
    const int it = m & 7;
    const int jt = m >> 3;
    const int i0 = it * 64;
    const int j0 = i0 - 50 + jt * 64;

    float* db = diag + (size_t)b * (PROWS * 128);

    // corner paint: consumed-but-unwritten cells of d in [1,64) U [972,1025) get BIG.
    // (116 rows; d in [64,972) is fully in-range/in-band, DP masks k>100 lanes itself.)
    if (m == 0) {
      for (int r = w; r < 116; r += 4) {
        const int d = (r < 63) ? (r + 1) : (909 + r);  // 1..63, 972..1024
        const int pp = d & 1;
        const int k = 2 * lane + pp;
        const int i = (d + k - 50) >> 1;  // even numerator, exact
        const int j = d - i;
        if (k > 100 || (unsigned)i >= TT || (unsigned)j >= TT)
          db[(size_t)(1 + ((d - 1) >> 1)) * 128 + 2 * lane + ((d - 1) & 1)] = BIGF;
      }
    }

    const float* x1b = x1 + (size_t)b * (TT * DD);
    const float* x2b = x2 + (size_t)b * (TT * DD);
    int gj = j0 + sr;
    gj = gj < 0 ? 0 : (gj > TT - 1 ? TT - 1 : gj);
    const float* pAg = x1b + (size_t)(i0 + sr) * DD + sq * 8;
    const float* pBg = x2b + (size_t)gj * DD + sq * 8;

    floatx16 acc = {};
    float pa = 0.f, pb = 0.f;

    for (int kc = 0; kc < DD; kc += 32) {
      const float4 a0 = *(const float4*)(pAg + kc);
      const float4 a1 = *(const float4*)(pAg + kc + 4);
      const float4 b0 = *(const float4*)(pBg + kc);
      const float4 b1 = *(const float4*)(pBg + kc + 4);
      pa += a0.x * a0.x + a0.y * a0.y + a0.z * a0.z + a0.w * a0.w;
      pa += a1.x * a1.x + a1.y * a1.y + a1.z * a1.z + a1.w * a1.w;
      pb += b0.x * b0.x + b0.y * b0.y + b0.z * b0.z + b0.w * b0.w;
      pb += b1.x * b1.x + b1.y * b1.y + b1.z * b1.z + b1.w * b1.w;
      __syncthreads();
      {
        bf16x8 va, vb;
        va[0] = (__bf16)a0.x; va[1] = (__bf16)a0.y; va[2] = (__bf16)a0.z; va[3] = (__bf16)a0.w;
        va[4] = (__bf16)a1.x; va[5] = (__bf16)a1.y; va[6] = (__bf16)a1.z; va[7] = (__bf16)a1.w;
        vb[0] = (__bf16)b0.x; vb[1] = (__bf16)b0.y; vb[2] = (__bf16)b0.z; vb[3] = (__bf16)b0.w;
        vb[4] = (__bf16)b1.x; vb[5] = (__bf16)b1.y; vb[6] = (__bf16)b1.z; vb[7] = (__bf16)b1.w;
        *(bf16x8*)dA = va;
        *(bf16x8*)dB = vb;
      }
      __syncthreads();
      const bf16x8 fa0 = *(const bf16x8*)fAp;
      const bf16x8 fb0 = *(const bf16x8*)fBp;
      const bf16x8 fa1 = *(const bf16x8*)(fAp + 16);
      const bf16x8 fb1 = *(const bf16x8*)(fBp + 16);
      acc = __builtin_amdgcn_mfma_f32_32x32x16_bf16(fa0, fb0, acc, 0, 0, 0);
      acc = __builtin_amdgcn_mfma_f32_32x32x16_bf16(fa1, fb1, acc, 0, 0, 0);
    }

    pa += __shfl_xor(pa, 1, 64); pa += __shfl_xor(pa, 2, 64);
    pb += __shfl_xor(pb, 1, 64); pb += __shfl_xor(pb, 2, 64);
    if (sq == 0) {
      rA[sr] = 1.0f / fmaxf(sqrtf(pa), 1e-8f);
      rB[sr] = 1.0f / fmaxf(sqrtf(pb), 1e-8f);
    }
    __syncthreads();

    {
      const int rj = wj * 32 + ln;
      const float r2 = rB[rj];
#pragma unroll
      for (int reg = 0; reg < 16; ++reg) {
        const int ri = wi * 32 + (reg & 3) + 8 * (reg >> 2) + 4 * kh;
        sC[ri * CST + rj] = 1.0f - acc[reg] * rA[ri] * r2;
      }
    }
    __syncthreads();

    // diag stores: wave w handles tile-diag rows r = w, w+4, ..., w+124 (d = d0 + r).
    // lane l holds band cell k = 2l + (d&1) from the LDS transpose (stride-65, conflict-free);
    // global addr = pair-interleaved: 64 lanes at stride 2 floats -> 512 B span, 8 lines.
    {
      const int d0 = i0 + j0;
      const int a65 = 65 * lane;
#pragma unroll 4
      for (int rr = 0; rr < 32; ++rr) {
        const int r = 4 * rr + w;
        const int d = d0 + r;
        const int pp = d & 1;
        const int roff = ((d + pp - 50) >> 1) - i0;
        const int ri = lane + roff;
        const int rj = r - ri;
        const int kband = 2 * lane + pp;
        const int jg = j0 + rj;
        if (((unsigned)ri < 64u) & ((unsigned)rj < 64u) & (kband <= 100) &
            ((unsigned)jg < (unsigned)TT)) {
          db[(size_t)(1 + ((d - 1) >> 1)) * 128 + 2 * lane + ((d - 1) & 1)] =
              sC[a65 + 65 * roff + r];
        }
      }
    }
  }
}

// ---------- Kernel C: DP with float2 rolling prefetch, zero-shuffle ----------
// Single wave per batch, no barriers. Lane l loads float2 at pair row p, offset 2l:
// v.x = cell k=2l+1 of d=2p+1, v.y = cell k=2l of d=2p+2 -- directly in band layout,
// no cross-lane ops (round-6's 4x ds_bpermute/pair chain cost eliminated).
// 63 in-flight float2 loads cover ~126 diagonals (~2000 cyc tolerance under the 6-bit
// vmcnt cap) > ~900 cyc miss latency -> chain-bound ~16-18 cyc/step, not latency-bound.
__global__ __launch_bounds__(64, 1) void dtw_dp_kernel(const float* __restrict__ diag,
                                                       float* __restrict__ out) {
  const int b = blockIdx.x;
  const int l = threadIdx.x;
  const bool inv_odd = (l >= 50);   // k=2l+1 > 100
  const bool inv_even = (l >= 51);  // k=2l   > 100
  const float* base = diag + (size_t)b * (PROWS * 128);

  const float* pP = base + 128 + 2 * l;  // pair 0 (d=1,2), lane slot
  float2 cr[64];                         // 64 pairs = 128 diagonals buffered
#pragma unroll
  for (int s = 0; s < 64; ++s) {
    cr[s] = *(const float2*)pP;
    pP += 128;  // next pair row
  }

  float prev2 = BIGF;
  const float c00 = base[51];                 // cell (0,0): d=0 slot per layout formula
  float prev1 = (l == 25) ? c00 : BIGF;
  float ans = BIGF;

  for (int o = 0; o < 8; ++o) {
#pragma unroll
    for (int u = 0; u < 64; ++u) {   // pair p = 64*o + u; slot index static (rule #20)
      const float2 v = cr[u];
      cr[u] = *(const float2*)pP;    // prefetch pair p+64 (max row 576 < PROWS, in-batch)
      pP += 128;
      // odd diagonal d = 2p+1
      const float c1 = inv_odd ? BIGF : v.x;
      const float sh = dpp_wave_shl1(prev1, BIGF);
      const float m3 = fminf(fminf(prev1, sh), prev2);
      prev2 = prev1;
      prev1 = c1 + m3;
      // even diagonal d = 2p+2
      const float c2 = inv_even ? BIGF : v.y;
      const float sh2 = dpp_wave_shr1(prev1, BIGF);
      const float m32 = fminf(fminf(sh2, prev1), prev2);
      prev2 = prev1;
      prev1 = c2 + m32;
      if (o == 7 && u == 62) ans = prev1;  // d = 1022 -> cell (511,511) at lane 25
      // pair 511 (d=1023,1024) consumed after ans; values irrelevant (finite)
    }
  }
  if (l == 25) out[b] = ans;
}

extern "C" void kernel_launch(void* const* d_in, const int* in_sizes, int n_in,
                              void* d_out, int out_size, void* d_ws, size_t ws_size,
                              hipStream_t stream) {
  const float* x1 = (const float*)d_in[0];
  const float* x2 = (const float*)d_in[1];
  float* out = (float*)d_out;
  float* diag = (float*)d_ws;  // 64 * 580 * 128 floats = 19.0 MB

  cost_kernel<<<768, 256, 0, stream>>>(x1, x2, diag);
  dtw_dp_kernel<<<NB, 64, 0, stream>>>(diag, out);
}